// Round 9
// baseline (422.104 us; speedup 1.0000x reference)
//
#include <hip/hip_runtime.h>
#include <stdint.h>

#define NR 32768
#define MM 8
#define NCLS 100
#define HALFN 1048576u
#define HSS 260   // fp16 stride for h plane rows: balanced banks for b64 frag reads
#define LGS 260   // float stride for logit rows
#define TOTALB (512 * 8 * 3)

typedef _Float16 h8 __attribute__((ext_vector_type(8)));
typedef _Float16 h4 __attribute__((ext_vector_type(4)));
typedef float f4 __attribute__((ext_vector_type(4)));
typedef unsigned long long ull;

// ---------------- threefry2x32 (exact JAX semantics) ----------------
__host__ __device__ inline void tf2x32(uint32_t k0, uint32_t k1, uint32_t x0, uint32_t x1,
                                       uint32_t& o0, uint32_t& o1) {
  uint32_t ks0 = k0, ks1 = k1, ks2 = k0 ^ k1 ^ 0x1BD11BDAu;
  x0 += ks0; x1 += ks1;
#define TFR(r) { x0 += x1; x1 = (x1 << r) | (x1 >> (32 - r)); x1 ^= x0; }
  TFR(13) TFR(15) TFR(26) TFR(6)  x0 += ks1; x1 += ks2 + 1u;
  TFR(17) TFR(29) TFR(16) TFR(24) x0 += ks2; x1 += ks0 + 2u;
  TFR(13) TFR(15) TFR(26) TFR(6)  x0 += ks0; x1 += ks1 + 3u;
  TFR(17) TFR(29) TFR(16) TFR(24) x0 += ks1; x1 += ks2 + 4u;
  TFR(13) TFR(15) TFR(26) TFR(6)  x0 += ks2; x1 += ks0 + 5u;
#undef TFR
  o0 = x0; o1 = x1;
}

__device__ inline uint32_t tf_bits(uint32_t k0, uint32_t k1, uint32_t i) {
  uint32_t o0, o1;
  if (i < HALFN) { tf2x32(k0, k1, i, i + HALFN, o0, o1); return o0; }
  else           { tf2x32(k0, k1, i - HALFN, i, o0, o1); return o1; }
}

// template dtype auto-detect: float32 {0,1.0f} / int32 {0,1} / bytes. 4 ones expected.
__device__ inline int load_tmpl(const void* p, int lane) {
  const unsigned* pi = (const unsigned*)p;
  unsigned w = pi[lane];
  ull okF = __ballot(w == 0u || w == 0x3F800000u);
  ull onF = __ballot(w == 0x3F800000u);
  ull okI = __ballot(w <= 1u);
  ull onI = __ballot(w == 1u);
  if (okF == ~0ull && __popcll(onF) == 4) return (w == 0x3F800000u) ? 1 : 0;
  if (okI == ~0ull && __popcll(onI) == 4) return (int)w;
  const unsigned char* pb = (const unsigned char*)p;
  return pb[lane] ? 1 : 0;
}

__device__ inline uint32_t rdlaneu(uint32_t v, int l) {
  return (uint32_t)__builtin_amdgcn_readlane((int)v, l);
}

__device__ inline uint32_t packh2(float a, float b) {
  union { _Float16 h[2]; uint32_t u; } cv;
  cv.h[0] = (_Float16)a; cv.h[1] = (_Float16)b;
  return cv.u;
}

// ---------------- stage1p: per-row transform + weight prep fused ----------------
// blocks 0..8191: per-row permute/flip/targets/y-scan (4 rows/block).
// blocks 8192..8447: W2 frag pack; 8448..8479: W1 frag pack; 8480..8504: cb64.
__global__ __launch_bounds__(256) void stage1p(
    const float* __restrict__ x, const int* __restrict__ y, const int* __restrict__ perm,
    const void* tmap, const void* traw,
    uint32_t km0, uint32_t km1, uint32_t kr0, uint32_t kr1,
    const float* __restrict__ W2, const float* __restrict__ W1,
    const float* __restrict__ centroids,
    _Float16* __restrict__ Wp, _Float16* __restrict__ Wp1, ull* __restrict__ cb64,
    uint32_t* __restrict__ xp16, uint32_t* __restrict__ xm16,
    ull* __restrict__ targ, ull* __restrict__ xb,
    float* __restrict__ winv, unsigned char* __restrict__ poslist, int* __restrict__ nposA) {
  int b = blockIdx.x, tid = threadIdx.x;
  if (b >= NR / 4) {
    int pb = b - NR / 4;
    if (pb < 256) {
      // W2: gid = ((m*8+kt)*16+NT)*64 + q*16+lr ; elem j = W2[m][kt*32+q*8+j][NT*16+lr]
      int gid = pb * 256 + tid;
      int lane6 = gid & 63, frag = gid >> 6;
      int NT = frag & 15, kt = (frag >> 4) & 7, m = frag >> 7;
      int q = lane6 >> 4, lr = lane6 & 15;
      const float* src = W2 + (size_t)m * 65536 + (size_t)(kt * 32 + q * 8) * 256 + NT * 16 + lr;
      h8 v;
#pragma unroll
      for (int j = 0; j < 8; j++) v[j] = (_Float16)src[j * 256];
      *(h8*)(Wp + (size_t)gid * 8) = v;
    } else if (pb < 288) {
      // W1 frag (m, t): lane(q,lr) j -> A[hid=t*16+lr][k=q*8+j]: q0 = W1[j][hid], else 0
      int idx = (pb - 256) * 256 + tid;  // 8192 total
      int lane = idx & 63, t = (idx >> 6) & 15, m = idx >> 10;
      int q = lane >> 4, lr = lane & 15;
      h8 v;
#pragma unroll
      for (int j = 0; j < 8; j++)
        v[j] = (q == 0) ? (_Float16)W1[(size_t)(m * 8 + j) * 256 + t * 16 + lr] : (_Float16)0.0f;
      *(h8*)(Wp1 + (size_t)idx * 8) = v;
    } else {
      // centroid bits: 4 classes per block, one wave each (25 blocks x 4 = 100)
      int c = (pb - 288) * 4 + (tid >> 6);
      int lane = tid & 63;
      ull bits = __ballot(centroids[c * 64 + perm[lane]] > 0.0f);
      if (lane == 0) cb64[c] = bits;
    }
    return;
  }

  int wv = tid >> 6, lane = tid & 63;
  int n = b * 4 + wv;

  int tm = load_tmpl(tmap, lane);
  int tr = load_tmpl(traw, lane);
  float xpv = x[n * 64 + perm[lane]];
  uint32_t i = (uint32_t)(n * 64 + lane);

  // rank by integer key: ((bits>>9)<<6)|lane == stable argsort of the uniform
  uint32_t bm = tf_bits(km0, km1, i);
  uint32_t br = tf_bits(kr0, kr1, i);
  uint32_t kmk = ((bm >> 9) << 6) | (uint32_t)lane;
  uint32_t krk = ((br >> 9) << 6) | (uint32_t)lane;
  int rank_m = 0, rank_r = 0;
#pragma unroll 16
  for (int k = 0; k < 64; k++) {
    rank_m += (rdlaneu(kmk, k) < kmk) ? 1 : 0;
    rank_r += (rdlaneu(krk, k) < krk) ? 1 : 0;
  }
  // deliver template bit to the lane holding that rank (mask[i] = template[lane ranked i])
  int flipm = __builtin_amdgcn_ds_permute(rank_m << 2, tm);
  int flipr = __builtin_amdgcn_ds_permute(rank_r << 2, tr);

  float xmv = flipm ? -xpv : xpv;
  float rfv = flipr ? -xpv : xpv;
  // fp16 outputs (identical rounding to former in-kernel cvt)
  float xp_o = __shfl_xor(xpv, 1);
  float xm_o = __shfl_xor(xmv, 1);
  if ((lane & 1) == 0) {
    xp16[n * 32 + (lane >> 1)] = packh2(xpv, xp_o);
    xm16[n * 32 + (lane >> 1)] = packh2(xmv, xm_o);
  }
  ull t64 = __ballot(rfv > 0.0f);
  ull b64v = __ballot(xpv > 0.0f);

  int c1 = y[(size_t)n * NCLS + lane] > 0;
  int c2 = (lane < NCLS - 64) ? (y[(size_t)n * NCLS + 64 + lane] > 0) : 0;
  ull p0 = __ballot(c1);
  ull p1 = __ballot(c2);
  int cnt0 = __popcll(p0);
  float cnt = (float)(cnt0 + __popcll(p1));

  // parallel poslist scatter (ascending class order preserved)
  unsigned char* pl = poslist + (size_t)n * 64;
  ull below = (lane == 0) ? 0ull : (~0ull >> (64 - lane));
  if (c1) pl[__popcll(p0 & below)] = (unsigned char)lane;
  if (c2) pl[cnt0 + __popcll(p1 & below)] = (unsigned char)(64 + lane);

  if (lane == 0) {
    targ[n] = t64;
    xb[n] = b64v;
    winv[n] = 1.0f / cnt;
    nposA[n] = cnt0 + __popcll(p1);
  }
}

// ---------------- fused MLP + loss epilogue + hamming slice + final reduce ----
// grid (512, 8, 3); block 512 (8 waves). z0 = map, z1 = net, z2 = hamming.
// Last-arriving block (device-scope ticket) performs the final output reduction.
__global__ __launch_bounds__(512, 6) void mapnet9(
    const uint32_t* __restrict__ Xm16, const uint32_t* __restrict__ Xp16,
    const _Float16* __restrict__ Wp1, const float* __restrict__ B1,
    const _Float16* __restrict__ Wp, const float* __restrict__ B2,
    const ull* __restrict__ targ, const float* __restrict__ winv,
    const unsigned char* __restrict__ poslist, const int* __restrict__ nposA,
    const ull* __restrict__ cb64, const ull* __restrict__ xb,
    float* __restrict__ accbuf, int* __restrict__ ticket, float* __restrict__ out) {
  __shared__ union {
    _Float16 h[64 * HSS];      // fp16 h-plane, 33280 B
    float lg[32 * LGS];        // logit staging, 33280 B (exact alias)
  } u;
  __shared__ float sl[3];      // block accumulators
  __shared__ int lastFlag;
  __shared__ float fs[2][5];
  const int tid = threadIdx.x, lane = tid & 63, wv = tid >> 6;
  const int q = lane >> 4, lr = lane & 15;
  const int m = blockIdx.y, pass = blockIdx.z;
  const int n0 = blockIdx.x * 64;
  if (tid < 3) sl[tid] = 0.0f;

  if (pass == 2) {
    // hamming + cnt: 8 rows per block (one per wave)
    __syncthreads();
    int flat = blockIdx.y * 512 + blockIdx.x;   // 0..4095
    int n = flat * 8 + wv;
    ull xv = xb[n];
    float px = (float)__popcll(xv);
    int np = nposA[n];
    float hs = 0.0f;
    if (lane < np) {
      int c = poslist[(size_t)n * 64 + lane];
      ull cb = cb64[c];
      hs = px + (float)__popcll(cb) - 2.0f * (float)__popcll(xv & cb);
    }
#pragma unroll
    for (int off = 1; off < 64; off <<= 1) hs += __shfl_xor(hs, off);
    if (lane == 0) {
      atomicAdd(&sl[0], hs);
      atomicAdd(&sl[1], (float)np);
    }
    __syncthreads();
    if (tid == 0) {
      float* slot = accbuf + (flat & 127) * 8;
      atomicAdd(&slot[3], sl[0]);
      atomicAdd(&slot[4], sl[1]);
    }
  } else {
    const uint32_t* Xin = pass ? Xp16 : Xm16;

    // ---- L1 (transposed): wave wv covers rowblock rb = wv&3, t-range (wv>>2)*8..+7
    const int rb = wv & 3, tbase = (wv >> 2) * 8;
    h8 af;
    {
      const _Float16* xsrc = (const _Float16*)(Xin + (size_t)(n0 + rb * 16 + lr) * 32) + m * 8;
      h8 xv = *(const h8*)xsrc;
      h8 zero = {(_Float16)0.0f, (_Float16)0.0f, (_Float16)0.0f, (_Float16)0.0f,
                 (_Float16)0.0f, (_Float16)0.0f, (_Float16)0.0f, (_Float16)0.0f};
      af = (q == 0) ? xv : zero;
    }
#pragma unroll 4
    for (int tt = 0; tt < 8; tt++) {
      int t = tbase + tt;
      h8 wfrag = *(const h8*)(Wp1 + ((size_t)(m * 16 + t) * 64 + lane) * 8);
      f4 z = __builtin_amdgcn_mfma_f32_16x16x32_f16(wfrag, af, (f4){0.f, 0.f, 0.f, 0.f}, 0, 0, 0);
      f4 b1v = *(const f4*)(B1 + m * 256 + t * 16 + q * 4);
      h4 pk;
#pragma unroll
      for (int reg = 0; reg < 4; reg++) {
        float zz = z[reg] + b1v[reg];
        // silu via v_rcp_f32 (1 ulp; h is rounded to fp16 afterwards -> exact enough)
        pk[reg] = (_Float16)(zz * __builtin_amdgcn_rcpf(1.0f + __expf(-zz)));
      }
      *(h4*)(u.h + (size_t)(rb * 16 + lr) * HSS + t * 16 + q * 4) = pk;
    }
    __syncthreads();

    // ---- K loop: wave wv owns cols wv*32 + nt*16 + lr (nt 0..1), 64 rows ----
    f4 acc4[4][2];
#pragma unroll
    for (int rt = 0; rt < 4; rt++)
#pragma unroll
      for (int nt = 0; nt < 2; nt++) acc4[rt][nt] = (f4){0.f, 0.f, 0.f, 0.f};

    const size_t wbase = (size_t)m * 65536;
#pragma unroll 2
    for (int kt = 0; kt < 8; kt++) {
      h8 ah[4];
#pragma unroll
      for (int rt = 0; rt < 4; rt++) {
        const _Float16* p = u.h + (rt * 16 + lr) * HSS + kt * 32 + q * 8;
        h4 lo = *(const h4*)p;
        h4 hi = *(const h4*)(p + 4);
        ah[rt] = __builtin_shufflevector(lo, hi, 0, 1, 2, 3, 4, 5, 6, 7);
      }
#pragma unroll
      for (int nt = 0; nt < 2; nt++) {
        h8 bh = *(const h8*)(Wp + wbase + (((size_t)kt * 16 + (wv * 2 + nt)) * 64 + lane) * 8);
#pragma unroll
        for (int rt = 0; rt < 4; rt++)
          acc4[rt][nt] = __builtin_amdgcn_mfma_f32_16x16x32_f16(ah[rt], bh, acc4[rt][nt], 0, 0, 0);
      }
    }

    float bv[2];
#pragma unroll
    for (int nt = 0; nt < 2; nt++) bv[nt] = B2[m * 256 + wv * 32 + nt * 16 + lr];

    // ---- epilogue: two 32-row phases through LDS; 16 lanes per row ----
    float partLoss = 0.0f, partHit = 0.0f;
    for (int ph = 0; ph < 2; ph++) {
      __syncthreads();
#pragma unroll
      for (int rt2 = 0; rt2 < 2; rt2++) {
        int rt = ph * 2 + rt2;
#pragma unroll
        for (int nt = 0; nt < 2; nt++)
#pragma unroll
          for (int reg = 0; reg < 4; reg++) {
            int row = rt2 * 16 + q * 4 + reg;
            u.lg[row * LGS + wv * 32 + nt * 16 + lr] = acc4[rt][nt][reg] + bv[nt];
          }
      }
      __syncthreads();
      int rl = tid >> 4;                   // local row 0..31
      int n = n0 + ph * 32 + rl;
      int cl = tid & 15;                   // 16 lanes per row; lane cl owns cols cl*4 + 64k + e
      const float* lrow = u.lg + rl * LGS;
      f4 vv[4];
#pragma unroll
      for (int k = 0; k < 4; k++) vv[k] = *(const f4*)(lrow + cl * 4 + k * 64);
      if (pass == 0) {
        float mv = -1e30f; int mi = 0;
#pragma unroll
        for (int k = 0; k < 4; k++)
#pragma unroll
          for (int e = 0; e < 4; e++) {
            float v = vv[k][e];
            int c = cl * 4 + k * 64 + e;
            if (v > mv) { mv = v; mi = c; }
          }
#pragma unroll
        for (int off = 1; off < 16; off <<= 1) {
          float om = __shfl_xor(mv, off); int oi = __shfl_xor(mi, off);
          if (om > mv || (om == mv && oi < mi)) { mv = om; mi = oi; }
        }
        float s = 0.0f;
#pragma unroll
        for (int k = 0; k < 4; k++)
#pragma unroll
          for (int e = 0; e < 4; e++) s += __expf(vv[k][e] - mv);
#pragma unroll
        for (int off = 1; off < 16; off <<= 1) s += __shfl_xor(s, off);
        if (cl == 0) {
          float lse = mv + __logf(s);
          int t = (int)((targ[n] >> (m * 8)) & 0xFFull);
          partLoss += lse - lrow[t];
          partHit += (mi == t) ? 1.0f : 0.0f;
        }
      } else {
        float s = 0.0f;
#pragma unroll
        for (int k = 0; k < 4; k++)
#pragma unroll
          for (int e = 0; e < 4; e++) s += __expf(vv[k][e]);
#pragma unroll
        for (int off = 1; off < 16; off <<= 1) s += __shfl_xor(s, off);
        int np = nposA[n];
        const unsigned char* pl = poslist + (size_t)n * 64;
        float sp = 0.0f;
        for (int j2 = cl; j2 < np; j2 += 16) {
          int c = pl[j2];
          int t = (int)((cb64[c] >> (m * 8)) & 0xFFull);
          sp += lrow[t];
        }
#pragma unroll
        for (int off = 1; off < 16; off <<= 1) sp += __shfl_xor(sp, off);
        if (cl == 0) partLoss += __logf(s) - winv[n] * sp;
      }
    }
    // lanes 0,16,32,48 of each wave hold row results
    partLoss += __shfl_xor(partLoss, 16); partHit += __shfl_xor(partHit, 16);
    partLoss += __shfl_xor(partLoss, 32); partHit += __shfl_xor(partHit, 32);
    if (lane == 0) {
      if (pass == 0) {
        atomicAdd(&sl[0], partLoss);
        atomicAdd(&sl[2], partHit);
      } else {
        atomicAdd(&sl[1], partLoss);
      }
    }
    __syncthreads();
    if (tid == 0) {
      float* slot = accbuf + (blockIdx.x & 127) * 8;
      if (pass == 0) {
        atomicAdd(&slot[0], sl[0]);
        atomicAdd(&slot[2], sl[2]);
      } else {
        atomicAdd(&slot[1], sl[1]);
      }
    }
  }

  // ---- completion ticket: last block reduces accbuf -> out ----
  if (tid == 0) {
    __threadfence();
    int old = atomicAdd(ticket, 1);
    lastFlag = (old == TOTALB - 1) ? 1 : 0;
  }
  __syncthreads();
  if (lastFlag) {
    float v0 = 0, v1 = 0, v2 = 0, v3 = 0, v4 = 0;
    if (tid < 128) {
      // L2-coherent reads of other blocks' device-scope atomic results
      v0 = atomicAdd(&accbuf[tid * 8 + 0], 0.0f);
      v1 = atomicAdd(&accbuf[tid * 8 + 1], 0.0f);
      v2 = atomicAdd(&accbuf[tid * 8 + 2], 0.0f);
      v3 = atomicAdd(&accbuf[tid * 8 + 3], 0.0f);
      v4 = atomicAdd(&accbuf[tid * 8 + 4], 0.0f);
    }
    if (tid < 128) {
#pragma unroll
      for (int off = 1; off < 64; off <<= 1) {
        v0 += __shfl_xor(v0, off); v1 += __shfl_xor(v1, off); v2 += __shfl_xor(v2, off);
        v3 += __shfl_xor(v3, off); v4 += __shfl_xor(v4, off);
      }
      if ((tid & 63) == 0) {
        fs[tid >> 6][0] = v0; fs[tid >> 6][1] = v1; fs[tid >> 6][2] = v2;
        fs[tid >> 6][3] = v3; fs[tid >> 6][4] = v4;
      }
    }
    __syncthreads();
    if (tid == 0) {
      float a0 = fs[0][0] + fs[1][0], a1 = fs[0][1] + fs[1][1], a2 = fs[0][2] + fs[1][2];
      float a3 = fs[0][3] + fs[1][3], a4 = fs[0][4] + fs[1][4];
      float netLoss = a1 / (float)NR;
      float mapLoss = a0 / (float)NR;
      out[0] = netLoss + mapLoss;
      out[1] = netLoss;
      out[2] = mapLoss;
      out[3] = a2 / (float)(NR * MM);
      out[4] = a3 / a4;
    }
  }
}

extern "C" void kernel_launch(void* const* d_in, const int* in_sizes, int n_in,
                              void* d_out, int out_size, void* d_ws, size_t ws_size,
                              hipStream_t stream) {
  const float* x = (const float*)d_in[0];
  const int* y = (const int*)d_in[1];
  const float* centroids = (const float*)d_in[2];
  const int* perm = (const int*)d_in[3];
  const void* tmap = d_in[4];
  const void* traw = d_in[5];
  const float* W1 = (const float*)d_in[6];
  const float* B1 = (const float*)d_in[7];
  const float* W2 = (const float*)d_in[8];
  const float* B2 = (const float*)d_in[9];
  float* out = (float*)d_out;

  char* w = (char*)d_ws;
  float* accbuf = (float*)w;                                  // 128 slots x 8 floats + ticket
  int* ticket = (int*)(w + 4088);                             // inside memset region
  uint32_t* xp16 = (uint32_t*)(w + 4096);                     // 4 MB (fp16 pairs)
  uint32_t* xm16 = xp16 + (size_t)NR * 32;                    // 4 MB
  ull* targ = (ull*)(xm16 + (size_t)NR * 32);                 // 256 KB
  ull* cb64 = targ + NR;                                      // 1 KB (128 slots)
  ull* xb = cb64 + 128;                                       // 256 KB
  float* winv = (float*)(xb + NR);                            // 128 KB
  int* nposA = (int*)(winv + NR);                             // 128 KB
  unsigned char* poslist = (unsigned char*)(nposA + NR);      // 2 MB
  _Float16* Wp = (_Float16*)(poslist + (size_t)NR * 64);      // 1 MB (fp16 frags)
  _Float16* Wp1 = Wp + (1 << 19);                             // 128 KB (L1 frags)

  hipMemsetAsync(accbuf, 0, 4096, stream);

  // jax.random.key(1) -> (0,1); split -> kmap=(w0(0,2), w0(1,3)), kraw=(w1(0,2), w1(1,3))
  uint32_t a0, b0, a1, b1;
  tf2x32(0u, 1u, 0u, 2u, a0, b0);
  tf2x32(0u, 1u, 1u, 3u, a1, b1);

  stage1p<<<NR / 4 + 313, 256, 0, stream>>>(x, y, perm, tmap, traw, a0, a1, b0, b1,
                                            W2, W1, centroids, Wp, Wp1, cb64,
                                            xp16, xm16, targ, xb, winv, poslist, nposA);
  dim3 g(NR / 64, MM, 3);
  mapnet9<<<g, 512, 0, stream>>>(xm16, xp16, Wp1, B1, Wp, B2, targ, winv, poslist, nposA,
                                 cb64, xb, accbuf, ticket, out);
}

// Round 10
// 260.543 us; speedup vs baseline: 1.6201x; 1.6201x over previous
//
#include <hip/hip_runtime.h>
#include <stdint.h>

#define NR 32768
#define MM 8
#define NCLS 100
#define HALFN 1048576u
#define HSS 260   // fp16 stride for h plane rows: balanced banks for b64 frag reads
#define LGS 260   // float stride for logit rows

typedef _Float16 h8 __attribute__((ext_vector_type(8)));
typedef _Float16 h4 __attribute__((ext_vector_type(4)));
typedef float f4 __attribute__((ext_vector_type(4)));
typedef unsigned long long ull;

// ---------------- threefry2x32 (exact JAX semantics) ----------------
__host__ __device__ inline void tf2x32(uint32_t k0, uint32_t k1, uint32_t x0, uint32_t x1,
                                       uint32_t& o0, uint32_t& o1) {
  uint32_t ks0 = k0, ks1 = k1, ks2 = k0 ^ k1 ^ 0x1BD11BDAu;
  x0 += ks0; x1 += ks1;
#define TFR(r) { x0 += x1; x1 = (x1 << r) | (x1 >> (32 - r)); x1 ^= x0; }
  TFR(13) TFR(15) TFR(26) TFR(6)  x0 += ks1; x1 += ks2 + 1u;
  TFR(17) TFR(29) TFR(16) TFR(24) x0 += ks2; x1 += ks0 + 2u;
  TFR(13) TFR(15) TFR(26) TFR(6)  x0 += ks0; x1 += ks1 + 3u;
  TFR(17) TFR(29) TFR(16) TFR(24) x0 += ks1; x1 += ks2 + 4u;
  TFR(13) TFR(15) TFR(26) TFR(6)  x0 += ks2; x1 += ks0 + 5u;
#undef TFR
  o0 = x0; o1 = x1;
}

__device__ inline uint32_t tf_bits(uint32_t k0, uint32_t k1, uint32_t i) {
  uint32_t o0, o1;
  if (i < HALFN) { tf2x32(k0, k1, i, i + HALFN, o0, o1); return o0; }
  else           { tf2x32(k0, k1, i - HALFN, i, o0, o1); return o1; }
}

// template dtype auto-detect: float32 {0,1.0f} / int32 {0,1} / bytes. 4 ones expected.
__device__ inline int load_tmpl(const void* p, int lane) {
  const unsigned* pi = (const unsigned*)p;
  unsigned w = pi[lane];
  ull okF = __ballot(w == 0u || w == 0x3F800000u);
  ull onF = __ballot(w == 0x3F800000u);
  ull okI = __ballot(w <= 1u);
  ull onI = __ballot(w == 1u);
  if (okF == ~0ull && __popcll(onF) == 4) return (w == 0x3F800000u) ? 1 : 0;
  if (okI == ~0ull && __popcll(onI) == 4) return (int)w;
  const unsigned char* pb = (const unsigned char*)p;
  return pb[lane] ? 1 : 0;
}

__device__ inline uint32_t rdlaneu(uint32_t v, int l) {
  return (uint32_t)__builtin_amdgcn_readlane((int)v, l);
}

__device__ inline uint32_t packh2(float a, float b) {
  union { _Float16 h[2]; uint32_t u; } cv;
  cv.h[0] = (_Float16)a; cv.h[1] = (_Float16)b;
  return cv.u;
}

// ---------------- stage1p: per-row transform + weight prep fused ----------------
// blocks 0..8191: per-row permute/flip/targets/y-scan (4 rows/block).
// blocks 8192..8447: W2 frag pack; 8448..8479: W1 frag pack; 8480..8504: cb64.
__global__ __launch_bounds__(256) void stage1p(
    const float* __restrict__ x, const int* __restrict__ y, const int* __restrict__ perm,
    const void* tmap, const void* traw,
    uint32_t km0, uint32_t km1, uint32_t kr0, uint32_t kr1,
    const float* __restrict__ W2, const float* __restrict__ W1,
    const float* __restrict__ centroids,
    _Float16* __restrict__ Wp, _Float16* __restrict__ Wp1, ull* __restrict__ cb64,
    uint32_t* __restrict__ xp16, uint32_t* __restrict__ xm16,
    ull* __restrict__ targ, ull* __restrict__ xb,
    float* __restrict__ winv, unsigned char* __restrict__ poslist, int* __restrict__ nposA) {
  int b = blockIdx.x, tid = threadIdx.x;
  if (b >= NR / 4) {
    int pb = b - NR / 4;
    if (pb < 256) {
      // W2: gid = ((m*8+kt)*16+NT)*64 + q*16+lr ; elem j = W2[m][kt*32+q*8+j][NT*16+lr]
      int gid = pb * 256 + tid;
      int lane6 = gid & 63, frag = gid >> 6;
      int NT = frag & 15, kt = (frag >> 4) & 7, m = frag >> 7;
      int q = lane6 >> 4, lr = lane6 & 15;
      const float* src = W2 + (size_t)m * 65536 + (size_t)(kt * 32 + q * 8) * 256 + NT * 16 + lr;
      h8 v;
#pragma unroll
      for (int j = 0; j < 8; j++) v[j] = (_Float16)src[j * 256];
      *(h8*)(Wp + (size_t)gid * 8) = v;
    } else if (pb < 288) {
      // W1 frag (m, t): lane(q,lr) j -> A[hid=t*16+lr][k=q*8+j]: q0 = W1[j][hid], else 0
      int idx = (pb - 256) * 256 + tid;  // 8192 total
      int lane = idx & 63, t = (idx >> 6) & 15, m = idx >> 10;
      int q = lane >> 4, lr = lane & 15;
      h8 v;
#pragma unroll
      for (int j = 0; j < 8; j++)
        v[j] = (q == 0) ? (_Float16)W1[(size_t)(m * 8 + j) * 256 + t * 16 + lr] : (_Float16)0.0f;
      *(h8*)(Wp1 + (size_t)idx * 8) = v;
    } else {
      // centroid bits: 4 classes per block, one wave each (25 blocks x 4 = 100)
      int c = (pb - 288) * 4 + (tid >> 6);
      int lane = tid & 63;
      ull bits = __ballot(centroids[c * 64 + perm[lane]] > 0.0f);
      if (lane == 0) cb64[c] = bits;
    }
    return;
  }

  int wv = tid >> 6, lane = tid & 63;
  int n = b * 4 + wv;

  int tm = load_tmpl(tmap, lane);
  int tr = load_tmpl(traw, lane);
  float xpv = x[n * 64 + perm[lane]];
  uint32_t i = (uint32_t)(n * 64 + lane);

  // rank by integer key: ((bits>>9)<<6)|lane == stable argsort of the uniform
  uint32_t bm = tf_bits(km0, km1, i);
  uint32_t br = tf_bits(kr0, kr1, i);
  uint32_t kmk = ((bm >> 9) << 6) | (uint32_t)lane;
  uint32_t krk = ((br >> 9) << 6) | (uint32_t)lane;
  int rank_m = 0, rank_r = 0;
#pragma unroll 16
  for (int k = 0; k < 64; k++) {
    rank_m += (rdlaneu(kmk, k) < kmk) ? 1 : 0;
    rank_r += (rdlaneu(krk, k) < krk) ? 1 : 0;
  }
  // deliver template bit to the lane holding that rank (mask[i] = template[lane ranked i])
  int flipm = __builtin_amdgcn_ds_permute(rank_m << 2, tm);
  int flipr = __builtin_amdgcn_ds_permute(rank_r << 2, tr);

  float xmv = flipm ? -xpv : xpv;
  float rfv = flipr ? -xpv : xpv;
  // fp16 outputs (identical rounding to former in-kernel cvt)
  float xp_o = __shfl_xor(xpv, 1);
  float xm_o = __shfl_xor(xmv, 1);
  if ((lane & 1) == 0) {
    xp16[n * 32 + (lane >> 1)] = packh2(xpv, xp_o);
    xm16[n * 32 + (lane >> 1)] = packh2(xmv, xm_o);
  }
  ull t64 = __ballot(rfv > 0.0f);
  ull b64v = __ballot(xpv > 0.0f);

  int c1 = y[(size_t)n * NCLS + lane] > 0;
  int c2 = (lane < NCLS - 64) ? (y[(size_t)n * NCLS + 64 + lane] > 0) : 0;
  ull p0 = __ballot(c1);
  ull p1 = __ballot(c2);
  int cnt0 = __popcll(p0);
  float cnt = (float)(cnt0 + __popcll(p1));

  // parallel poslist scatter (ascending class order preserved)
  unsigned char* pl = poslist + (size_t)n * 64;
  ull below = (lane == 0) ? 0ull : (~0ull >> (64 - lane));
  if (c1) pl[__popcll(p0 & below)] = (unsigned char)lane;
  if (c2) pl[cnt0 + __popcll(p1 & below)] = (unsigned char)(64 + lane);

  if (lane == 0) {
    targ[n] = t64;
    xb[n] = b64v;
    winv[n] = 1.0f / cnt;
    nposA[n] = cnt0 + __popcll(p1);
  }
}

// ---------------- fused MLP + loss epilogue + hamming slice ----
// grid (512, 8, 3); block 512 (8 waves). z0 = map, z1 = net, z2 = hamming.
// NOTE: no device-scope fence/ticket here — R9 showed a per-block __threadfence
// costs ~170 µs across the grid; the separate finalk launch is far cheaper.
__global__ __launch_bounds__(512, 6) void mapnet8(
    const uint32_t* __restrict__ Xm16, const uint32_t* __restrict__ Xp16,
    const _Float16* __restrict__ Wp1, const float* __restrict__ B1,
    const _Float16* __restrict__ Wp, const float* __restrict__ B2,
    const ull* __restrict__ targ, const float* __restrict__ winv,
    const unsigned char* __restrict__ poslist, const int* __restrict__ nposA,
    const ull* __restrict__ cb64, const ull* __restrict__ xb,
    float* __restrict__ accbuf) {
  __shared__ union {
    _Float16 h[64 * HSS];      // fp16 h-plane, 33280 B
    float lg[32 * LGS];        // logit staging, 33280 B (exact alias)
  } u;
  __shared__ float sl[3];      // block accumulators
  const int tid = threadIdx.x, lane = tid & 63, wv = tid >> 6;
  const int q = lane >> 4, lr = lane & 15;
  const int m = blockIdx.y, pass = blockIdx.z;
  const int n0 = blockIdx.x * 64;
  if (tid < 3) sl[tid] = 0.0f;

  if (pass == 2) {
    // hamming + cnt: 8 rows per block (one per wave)
    __syncthreads();
    int flat = blockIdx.y * 512 + blockIdx.x;   // 0..4095
    int n = flat * 8 + wv;
    ull xv = xb[n];
    float px = (float)__popcll(xv);
    int np = nposA[n];
    float hs = 0.0f;
    if (lane < np) {
      int c = poslist[(size_t)n * 64 + lane];
      ull cb = cb64[c];
      hs = px + (float)__popcll(cb) - 2.0f * (float)__popcll(xv & cb);
    }
#pragma unroll
    for (int off = 1; off < 64; off <<= 1) hs += __shfl_xor(hs, off);
    if (lane == 0) {
      atomicAdd(&sl[0], hs);
      atomicAdd(&sl[1], (float)np);
    }
    __syncthreads();
    if (tid == 0) {
      float* slot = accbuf + (flat & 127) * 8;
      atomicAdd(&slot[3], sl[0]);
      atomicAdd(&slot[4], sl[1]);
    }
    return;
  }

  const uint32_t* Xin = pass ? Xp16 : Xm16;

  // ---- L1 (transposed): wave wv covers rowblock rb = wv&3, t-range (wv>>2)*8..+7
  const int rb = wv & 3, tbase = (wv >> 2) * 8;
  h8 af;
  {
    const _Float16* xsrc = (const _Float16*)(Xin + (size_t)(n0 + rb * 16 + lr) * 32) + m * 8;
    h8 xv = *(const h8*)xsrc;
    h8 zero = {(_Float16)0.0f, (_Float16)0.0f, (_Float16)0.0f, (_Float16)0.0f,
               (_Float16)0.0f, (_Float16)0.0f, (_Float16)0.0f, (_Float16)0.0f};
    af = (q == 0) ? xv : zero;
  }
#pragma unroll 4
  for (int tt = 0; tt < 8; tt++) {
    int t = tbase + tt;
    h8 wfrag = *(const h8*)(Wp1 + ((size_t)(m * 16 + t) * 64 + lane) * 8);
    f4 z = __builtin_amdgcn_mfma_f32_16x16x32_f16(wfrag, af, (f4){0.f, 0.f, 0.f, 0.f}, 0, 0, 0);
    f4 b1v = *(const f4*)(B1 + m * 256 + t * 16 + q * 4);
    h4 pk;
#pragma unroll
    for (int reg = 0; reg < 4; reg++) {
      float zz = z[reg] + b1v[reg];
      // silu via v_rcp_f32 (1 ulp; h is rounded to fp16 afterwards -> exact enough)
      pk[reg] = (_Float16)(zz * __builtin_amdgcn_rcpf(1.0f + __expf(-zz)));
    }
    *(h4*)(u.h + (size_t)(rb * 16 + lr) * HSS + t * 16 + q * 4) = pk;
  }
  __syncthreads();

  // ---- K loop: wave wv owns cols wv*32 + nt*16 + lr (nt 0..1), 64 rows ----
  f4 acc4[4][2];
#pragma unroll
  for (int rt = 0; rt < 4; rt++)
#pragma unroll
    for (int nt = 0; nt < 2; nt++) acc4[rt][nt] = (f4){0.f, 0.f, 0.f, 0.f};

  const size_t wbase = (size_t)m * 65536;
#pragma unroll 2
  for (int kt = 0; kt < 8; kt++) {
    h8 ah[4];
#pragma unroll
    for (int rt = 0; rt < 4; rt++) {
      const _Float16* p = u.h + (rt * 16 + lr) * HSS + kt * 32 + q * 8;
      h4 lo = *(const h4*)p;
      h4 hi = *(const h4*)(p + 4);
      ah[rt] = __builtin_shufflevector(lo, hi, 0, 1, 2, 3, 4, 5, 6, 7);
    }
#pragma unroll
    for (int nt = 0; nt < 2; nt++) {
      h8 bh = *(const h8*)(Wp + wbase + (((size_t)kt * 16 + (wv * 2 + nt)) * 64 + lane) * 8);
#pragma unroll
      for (int rt = 0; rt < 4; rt++)
        acc4[rt][nt] = __builtin_amdgcn_mfma_f32_16x16x32_f16(ah[rt], bh, acc4[rt][nt], 0, 0, 0);
    }
  }

  float bv[2];
#pragma unroll
  for (int nt = 0; nt < 2; nt++) bv[nt] = B2[m * 256 + wv * 32 + nt * 16 + lr];

  // ---- epilogue: two 32-row phases through LDS; 16 lanes per row ----
  float partLoss = 0.0f, partHit = 0.0f;
  for (int ph = 0; ph < 2; ph++) {
    __syncthreads();
#pragma unroll
    for (int rt2 = 0; rt2 < 2; rt2++) {
      int rt = ph * 2 + rt2;
#pragma unroll
      for (int nt = 0; nt < 2; nt++)
#pragma unroll
        for (int reg = 0; reg < 4; reg++) {
          int row = rt2 * 16 + q * 4 + reg;
          u.lg[row * LGS + wv * 32 + nt * 16 + lr] = acc4[rt][nt][reg] + bv[nt];
        }
    }
    __syncthreads();
    int rl = tid >> 4;                   // local row 0..31
    int n = n0 + ph * 32 + rl;
    int cl = tid & 15;                   // 16 lanes per row; lane cl owns cols cl*4 + 64k + e
    const float* lrow = u.lg + rl * LGS;
    f4 vv[4];
#pragma unroll
    for (int k = 0; k < 4; k++) vv[k] = *(const f4*)(lrow + cl * 4 + k * 64);
    if (pass == 0) {
      float mv = -1e30f; int mi = 0;
#pragma unroll
      for (int k = 0; k < 4; k++)
#pragma unroll
        for (int e = 0; e < 4; e++) {
          float v = vv[k][e];
          int c = cl * 4 + k * 64 + e;
          if (v > mv) { mv = v; mi = c; }
        }
#pragma unroll
      for (int off = 1; off < 16; off <<= 1) {
        float om = __shfl_xor(mv, off); int oi = __shfl_xor(mi, off);
        if (om > mv || (om == mv && oi < mi)) { mv = om; mi = oi; }
      }
      float s = 0.0f;
#pragma unroll
      for (int k = 0; k < 4; k++)
#pragma unroll
        for (int e = 0; e < 4; e++) s += __expf(vv[k][e] - mv);
#pragma unroll
      for (int off = 1; off < 16; off <<= 1) s += __shfl_xor(s, off);
      if (cl == 0) {
        float lse = mv + __logf(s);
        int t = (int)((targ[n] >> (m * 8)) & 0xFFull);
        partLoss += lse - lrow[t];
        partHit += (mi == t) ? 1.0f : 0.0f;
      }
    } else {
      float s = 0.0f;
#pragma unroll
      for (int k = 0; k < 4; k++)
#pragma unroll
        for (int e = 0; e < 4; e++) s += __expf(vv[k][e]);
#pragma unroll
      for (int off = 1; off < 16; off <<= 1) s += __shfl_xor(s, off);
      int np = nposA[n];
      const unsigned char* pl = poslist + (size_t)n * 64;
      float sp = 0.0f;
      for (int j2 = cl; j2 < np; j2 += 16) {
        int c = pl[j2];
        int t = (int)((cb64[c] >> (m * 8)) & 0xFFull);
        sp += lrow[t];
      }
#pragma unroll
      for (int off = 1; off < 16; off <<= 1) sp += __shfl_xor(sp, off);
      if (cl == 0) partLoss += __logf(s) - winv[n] * sp;
    }
  }
  // lanes 0,16,32,48 of each wave hold row results
  partLoss += __shfl_xor(partLoss, 16); partHit += __shfl_xor(partHit, 16);
  partLoss += __shfl_xor(partLoss, 32); partHit += __shfl_xor(partHit, 32);
  if (lane == 0) {
    if (pass == 0) {
      atomicAdd(&sl[0], partLoss);
      atomicAdd(&sl[2], partHit);
    } else {
      atomicAdd(&sl[1], partLoss);
    }
  }
  __syncthreads();
  if (tid == 0) {
    float* slot = accbuf + (blockIdx.x & 127) * 8;
    if (pass == 0) {
      atomicAdd(&slot[0], sl[0]);
      atomicAdd(&slot[2], sl[2]);
    } else {
      atomicAdd(&slot[1], sl[1]);
    }
  }
}

__global__ __launch_bounds__(128) void finalk(const float* __restrict__ accbuf, float* __restrict__ out) {
  int t = threadIdx.x;  // 0..127
  float v0 = accbuf[t * 8 + 0], v1 = accbuf[t * 8 + 1], v2 = accbuf[t * 8 + 2];
  float v3 = accbuf[t * 8 + 3], v4 = accbuf[t * 8 + 4];
#pragma unroll
  for (int off = 1; off < 64; off <<= 1) {
    v0 += __shfl_xor(v0, off); v1 += __shfl_xor(v1, off); v2 += __shfl_xor(v2, off);
    v3 += __shfl_xor(v3, off); v4 += __shfl_xor(v4, off);
  }
  __shared__ float s[2][5];
  if ((t & 63) == 0) {
    s[t >> 6][0] = v0; s[t >> 6][1] = v1; s[t >> 6][2] = v2; s[t >> 6][3] = v3; s[t >> 6][4] = v4;
  }
  __syncthreads();
  if (t == 0) {
    float a0 = s[0][0] + s[1][0], a1 = s[0][1] + s[1][1], a2 = s[0][2] + s[1][2];
    float a3 = s[0][3] + s[1][3], a4 = s[0][4] + s[1][4];
    float netLoss = a1 / (float)NR;
    float mapLoss = a0 / (float)NR;
    out[0] = netLoss + mapLoss;
    out[1] = netLoss;
    out[2] = mapLoss;
    out[3] = a2 / (float)(NR * MM);
    out[4] = a3 / a4;
  }
}

extern "C" void kernel_launch(void* const* d_in, const int* in_sizes, int n_in,
                              void* d_out, int out_size, void* d_ws, size_t ws_size,
                              hipStream_t stream) {
  const float* x = (const float*)d_in[0];
  const int* y = (const int*)d_in[1];
  const float* centroids = (const float*)d_in[2];
  const int* perm = (const int*)d_in[3];
  const void* tmap = d_in[4];
  const void* traw = d_in[5];
  const float* W1 = (const float*)d_in[6];
  const float* B1 = (const float*)d_in[7];
  const float* W2 = (const float*)d_in[8];
  const float* B2 = (const float*)d_in[9];
  float* out = (float*)d_out;

  char* w = (char*)d_ws;
  float* accbuf = (float*)w;                                  // 128 slots x 8 floats = 4 KB
  uint32_t* xp16 = (uint32_t*)(w + 4096);                     // 4 MB (fp16 pairs)
  uint32_t* xm16 = xp16 + (size_t)NR * 32;                    // 4 MB
  ull* targ = (ull*)(xm16 + (size_t)NR * 32);                 // 256 KB
  ull* cb64 = targ + NR;                                      // 1 KB (128 slots)
  ull* xb = cb64 + 128;                                       // 256 KB
  float* winv = (float*)(xb + NR);                            // 128 KB
  int* nposA = (int*)(winv + NR);                             // 128 KB
  unsigned char* poslist = (unsigned char*)(nposA + NR);      // 2 MB
  _Float16* Wp = (_Float16*)(poslist + (size_t)NR * 64);      // 1 MB (fp16 frags)
  _Float16* Wp1 = Wp + (1 << 19);                             // 128 KB (L1 frags)

  hipMemsetAsync(accbuf, 0, 4096, stream);

  // jax.random.key(1) -> (0,1); split -> kmap=(w0(0,2), w0(1,3)), kraw=(w1(0,2), w1(1,3))
  uint32_t a0, b0, a1, b1;
  tf2x32(0u, 1u, 0u, 2u, a0, b0);
  tf2x32(0u, 1u, 1u, 3u, a1, b1);

  stage1p<<<NR / 4 + 313, 256, 0, stream>>>(x, y, perm, tmap, traw, a0, a1, b0, b1,
                                            W2, W1, centroids, Wp, Wp1, cb64,
                                            xp16, xm16, targ, xb, winv, poslist, nposA);
  dim3 g(NR / 64, MM, 3);
  mapnet8<<<g, 512, 0, stream>>>(xm16, xp16, Wp1, B1, Wp, B2, targ, winv, poslist, nposA,
                                 cb64, xb, accbuf);
  finalk<<<1, 128, 0, stream>>>(accbuf, out);
}